// Round 2
// baseline (229.264 us; speedup 1.0000x reference)
//
#include <hip/hip_runtime.h>

#define NDIM 4096
#define B_LG 256
#define B_SM 256
#define R_LG 64
#define R_SM 16

// One 256-thread block computes one batch's GEMV: y[r] = sum_d x[d] * A[d][r].
// All tensors are float32 (harness upcasts the reference's fp16).
// A is [D][R] row-major (r contiguous). Each thread loads 16B (4 floats of
// consecutive r) per iteration; the block reads a contiguous 4KB chunk of A.
template<int R>
__device__ __forceinline__ void lora_gemv_block(
    const float* __restrict__ xb,   // [NDIM]
    const float* __restrict__ Ab,   // [NDIM][R]
    float* __restrict__ yb)         // [R]
{
    constexpr int VEC  = 4;          // floats per 16B load
    constexpr int LPR  = R / VEC;    // lanes per A-row: 16 (R=64) or 4 (R=16)
    constexpr int ROWS = 256 / LPR;  // A-rows per block-iter: 16 or 64
    constexpr int ITERS = NDIM / ROWS;

    __shared__ float xs[NDIM];             // 16 KB
    __shared__ float red[4][LPR][VEC];     // per-wave partials

    const int t = threadIdx.x;

    // Stage x row into LDS (coalesced 16B loads).
    {
        const float4* src = reinterpret_cast<const float4*>(xb);
        float4* dst = reinterpret_cast<float4*>(xs);
        for (int i = t; i < NDIM / 4; i += 256) dst[i] = src[i];
    }
    __syncthreads();

    const int d_sub  = t / LPR;          // A-row within the iter chunk
    const int r_base = (t % LPR) * VEC;  // 4-column slice

    float acc[VEC];
#pragma unroll
    for (int j = 0; j < VEC; ++j) acc[j] = 0.0f;

#pragma unroll 4
    for (int i = 0; i < ITERS; ++i) {
        const int d = i * ROWS + d_sub;
        const float4 av = *reinterpret_cast<const float4*>(Ab + (size_t)d * R + r_base);
        const float xv = xs[d];
        acc[0] = fmaf(xv, av.x, acc[0]);
        acc[1] = fmaf(xv, av.y, acc[1]);
        acc[2] = fmaf(xv, av.z, acc[2]);
        acc[3] = fmaf(xv, av.w, acc[3]);
    }

    // Wave-level tree reduction: lanes with equal (lane % LPR) share an r-slice.
    // 64 % LPR == 0, so t % LPR == lane % LPR.
#pragma unroll
    for (int off = 32; off >= LPR; off >>= 1) {
#pragma unroll
        for (int j = 0; j < VEC; ++j)
            acc[j] += __shfl_down(acc[j], off, 64);
    }

    const int wave = t >> 6;
    const int lane = t & 63;
    if (lane < LPR) {
#pragma unroll
        for (int j = 0; j < VEC; ++j) red[wave][lane][j] = acc[j];
    }
    __syncthreads();

    // Cross-wave finish: thread r sums the 4 wave partials.
    if (t < R) {
        const int rl = t / VEC, j = t % VEC;
        yb[t] = red[0][rl][j] + red[1][rl][j] + red[2][rl][j] + red[3][rl][j];
    }
}

__global__ __launch_bounds__(256)
void SequentialLoraA_kernel(const float* __restrict__ x,
                            const int* __restrict__ wids_l,
                            const int* __restrict__ wids_s,
                            const float* __restrict__ Al,
                            const float* __restrict__ As,
                            float* __restrict__ out)
{
    const int b = blockIdx.x;
    if (b < B_LG) {
        const int wid = wids_l[b];
        lora_gemv_block<R_LG>(x + (size_t)b * NDIM,
                              Al + (size_t)wid * NDIM * R_LG,
                              out + (size_t)b * R_LG);
    } else {
        const int bs = b - B_LG;
        const int wid = wids_s[bs];
        lora_gemv_block<R_SM>(x + (size_t)b * NDIM,
                              As + (size_t)wid * NDIM * R_SM,
                              out + (size_t)B_LG * R_LG + (size_t)bs * R_SM);
    }
}

extern "C" void kernel_launch(void* const* d_in, const int* in_sizes, int n_in,
                              void* d_out, int out_size, void* d_ws, size_t ws_size,
                              hipStream_t stream) {
    const float* x      = (const float*)d_in[0];
    const int*   wids_l = (const int*)d_in[1];
    const int*   wids_s = (const int*)d_in[2];
    const float* Al     = (const float*)d_in[3];
    const float* As     = (const float*)d_in[4];
    float* out = (float*)d_out;

    SequentialLoraA_kernel<<<B_LG + B_SM, 256, 0, stream>>>(x, wids_l, wids_s, Al, As, out);
}